// Round 1
// baseline (294.371 us; speedup 1.0000x reference)
//
#include <hip/hip_runtime.h>

// C51 distributional projection.
// next_dist: [B,51] f32 (rows sum to 1), rewards: [B] f32, bootstrap: [B] f32 (0/1).
// out: [B,51] f32 projected distribution.
//
// Strategy: block = 256 threads owns ROWS=64 consecutive rows (3264 contiguous
// f32 elements). Flat LDS accumulator == the output slab, so every global
// access (load next_dist, store out) is a contiguous coalesced stream and
// every LDS access is stride-1 (conflict-free). Row-local dual scatter-add via
// LDS atomicAdd (ds_add_f32).

namespace {

constexpr int NA    = 51;
constexpr int ROWS  = 64;
constexpr int BLOCK = 256;
constexpr int ELEMS = ROWS * NA;   // 3264

__global__ __launch_bounds__(BLOCK)
void c51_project(const float* __restrict__ next_dist,
                 const float* __restrict__ rewards,
                 const float* __restrict__ bootstrap,
                 float* __restrict__ out,
                 int B)
{
    __shared__ __align__(16) float acc[ELEMS];
    __shared__ float s_r[ROWS];
    __shared__ float s_g[ROWS];
    __shared__ float s_z[NA];

    const int tid       = threadIdx.x;
    const int base_row  = blockIdx.x * ROWS;
    const int rows_here = min(ROWS, B - base_row);
    const int elems_here = rows_here * NA;
    const long long base_elem = (long long)base_row * NA;

    if (tid < rows_here) {
        s_r[tid] = rewards[base_row + tid];
        s_g[tid] = bootstrap[base_row + tid] * 0.99f;  // bootstrap * DISCOUNT
    }
    if (tid < NA) {
        // match numpy linspace: f64 compute, cast f32. z[50] -> exactly 10.0f.
        s_z[tid] = (float)(-10.0 + (double)tid * 0.4);
    }
    for (int i = tid; i < ELEMS; i += BLOCK) acc[i] = 0.0f;
    __syncthreads();

    for (int e = tid; e < elems_here; e += BLOCK) {
        const unsigned ue   = (unsigned)e;
        const unsigned row  = ue / (unsigned)NA;        // magic-mul div
        const int      atom = (int)(ue - row * (unsigned)NA);
        const int  rowbase  = e - atom;                 // row * 51

        const float d = next_dist[base_elem + e];       // coalesced stream

        // target_z = r + (bootstrap*0.99)*z_j, clipped to [-10,10]
        float t = s_r[row] + s_g[row] * s_z[atom];
        t = fminf(fmaxf(t, -10.0f), 10.0f);
        // b = (t - V_MIN)/delta_z ; 1/0.4f rounds to exactly 2.5f, and the
        // clamp boundaries give exact 0.0 / 50.0 either way.
        const float b = (t + 10.0f) * 2.5f;

        int lower = (int)floorf(b);
        int upper = (int)ceilf(b);
        if (lower == upper) {                            // exact-integer bin
            if (lower > 0) lower -= 1; else upper += 1;
        }
        const float wl = d * ((float)upper - b);
        const float wu = d * (b - (float)lower);

        atomicAdd(&acc[rowbase + lower], wl);            // ds_add_f32
        atomicAdd(&acc[rowbase + upper], wu);
    }
    __syncthreads();

    if (elems_here == ELEMS) {
        // full block: vectorized contiguous copy LDS -> global
        float4* __restrict__ o4 = (float4*)(out + base_elem);
        const float4* __restrict__ a4 = (const float4*)acc;
        for (int v = tid; v < ELEMS / 4; v += BLOCK) o4[v] = a4[v];
    } else {
        for (int e = tid; e < elems_here; e += BLOCK) out[base_elem + e] = acc[e];
    }
}

} // namespace

extern "C" void kernel_launch(void* const* d_in, const int* in_sizes, int n_in,
                              void* d_out, int out_size, void* d_ws, size_t ws_size,
                              hipStream_t stream)
{
    const float* next_dist = (const float*)d_in[0];
    const float* rewards   = (const float*)d_in[1];
    const float* bootstrap = (const float*)d_in[2];
    float* out = (float*)d_out;

    const int B = in_sizes[1];                 // rewards element count
    const int nblocks = (B + ROWS - 1) / ROWS; // 8192 for B=524288

    c51_project<<<dim3(nblocks), dim3(BLOCK), 0, stream>>>(
        next_dist, rewards, bootstrap, out, B);
}

// Round 2
// 287.133 us; speedup vs baseline: 1.0252x; 1.0252x over previous
//
#include <hip/hip_runtime.h>

// C51 distributional projection.
// next_dist: [B,51] f32 (rows sum to 1), rewards: [B] f32, bootstrap: [B] f32 (0/1).
// out: [B,51] f32 projected distribution.
//
// Strategy: block = 256 threads owns ROWS=64 consecutive rows (3264 contiguous
// f32 elements). Flat LDS accumulator == the output slab, so every global
// access (load next_dist, store out) is a contiguous coalesced float4 stream
// and every LDS access is stride-1 (conflict-free). Row-local dual scatter-add
// via native ds_add_f32 (fire-and-forget; __hip_atomic_fetch_add with
// workgroup scope — plain atomicAdd lowers to a CAS retry loop, which was the
// R1 latency bottleneck).

namespace {

constexpr int NA    = 51;
constexpr int ROWS  = 64;
constexpr int BLOCK = 256;
constexpr int ELEMS = ROWS * NA;   // 3264 (divisible by 4)

__device__ __forceinline__ void lds_add(float* p, float v) {
    // relaxed, workgroup-scope -> native ds_add_f32 (no return, no CAS loop)
    __hip_atomic_fetch_add(p, v, __ATOMIC_RELAXED, __HIP_MEMORY_SCOPE_WORKGROUP);
}

__device__ __forceinline__ void project_one(float d, int e,
                                            const float2* s_rg, float* acc) {
    const unsigned ue   = (unsigned)e;
    const unsigned row  = ue / (unsigned)NA;          // magic-mul div
    const int      atom = (int)(ue - row * (unsigned)NA);
    const int   rowbase = e - atom;                   // row * 51

    const float2 rg = s_rg[row];                      // one ds_read_b64
    // z_j = -10 + 0.4*j (f32; off-by-ulp vs np linspace moves O(ulp*d) mass)
    const float z = fmaf((float)atom, 0.4f, -10.0f);
    float t = fmaf(rg.y, z, rg.x);                    // r + (bootstrap*0.99)*z
    t = fminf(fmaxf(t, -10.0f), 10.0f);
    const float b = (t + 10.0f) * 2.5f;               // in [0, 50]

    int lower = (int)floorf(b);
    int upper = (int)ceilf(b);
    if (lower == upper) {                             // exact-integer bin
        if (lower > 0) lower -= 1; else upper += 1;
    }
    lds_add(&acc[rowbase + lower], d * ((float)upper - b));
    lds_add(&acc[rowbase + upper], d * (b - (float)lower));
}

__global__ __launch_bounds__(BLOCK)
void c51_project(const float* __restrict__ next_dist,
                 const float* __restrict__ rewards,
                 const float* __restrict__ bootstrap,
                 float* __restrict__ out,
                 int B)
{
    __shared__ __align__(16) float acc[ELEMS];
    __shared__ float2 s_rg[ROWS];

    const int tid       = threadIdx.x;
    const int base_row  = blockIdx.x * ROWS;
    const int rows_here = min(ROWS, B - base_row);
    const int elems_here = rows_here * NA;
    const long long base_elem = (long long)base_row * NA;

    if (tid < rows_here) {
        s_rg[tid] = make_float2(rewards[base_row + tid],
                                bootstrap[base_row + tid] * 0.99f);
    }
    for (int i = tid; i < ELEMS; i += BLOCK) acc[i] = 0.0f;
    __syncthreads();

    if (elems_here == ELEMS) {
        // full block: float4 streaming loads
        const float4* __restrict__ in4 = (const float4*)(next_dist + base_elem);
        for (int v = tid; v < ELEMS / 4; v += BLOCK) {
            const float4 d4 = in4[v];
            const int e0 = v * 4;
            project_one(d4.x, e0 + 0, s_rg, acc);
            project_one(d4.y, e0 + 1, s_rg, acc);
            project_one(d4.z, e0 + 2, s_rg, acc);
            project_one(d4.w, e0 + 3, s_rg, acc);
        }
    } else {
        for (int e = tid; e < elems_here; e += BLOCK)
            project_one(next_dist[base_elem + e], e, s_rg, acc);
    }
    __syncthreads();

    if (elems_here == ELEMS) {
        float4* __restrict__ o4 = (float4*)(out + base_elem);
        const float4* __restrict__ a4 = (const float4*)acc;
        for (int v = tid; v < ELEMS / 4; v += BLOCK) o4[v] = a4[v];
    } else {
        for (int e = tid; e < elems_here; e += BLOCK) out[base_elem + e] = acc[e];
    }
}

} // namespace

extern "C" void kernel_launch(void* const* d_in, const int* in_sizes, int n_in,
                              void* d_out, int out_size, void* d_ws, size_t ws_size,
                              hipStream_t stream)
{
    const float* next_dist = (const float*)d_in[0];
    const float* rewards   = (const float*)d_in[1];
    const float* bootstrap = (const float*)d_in[2];
    float* out = (float*)d_out;

    const int B = in_sizes[1];                 // rewards element count
    const int nblocks = (B + ROWS - 1) / ROWS; // 8192 for B=524288

    c51_project<<<dim3(nblocks), dim3(BLOCK), 0, stream>>>(
        next_dist, rewards, bootstrap, out, B);
}

// Round 3
// 54.120 us; speedup vs baseline: 5.4392x; 5.3055x over previous
//
#include <hip/hip_runtime.h>

// C51 distributional projection — zero-atomic formulation.
//
// R1/R2 evidence: with 2 LDS atomic adds per element the kernel sat at ~290 us
// with every pipe idle (VALUBusy 8.5%, HBM 7%, MfmaUtil 0) regardless of
// atomic flavor (CAS loop vs native ds_add_f32) -> cost tracked the ATOMIC
// COUNT. This version has no atomics at all:
//
//   - block of 256 threads owns 256 rows; LDS holds the block's [256][51] slab
//     (52,224 B, flat row-major == global layout, so staging in and storing
//     out are contiguous coalesced float4 streams).
//   - each thread reads its own 51-atom row into registers (fully unrolled,
//     static indices; 51t+j mod 32 banks -> exactly 2 lanes/bank = free).
//   - key property: b_j = clip(2.5r + 25 + 0.99*beta*(j-25), 0, 50) is
//     monotone non-decreasing in j with step 0.99 < 1, and after the
//     integer-bin adjustment upper == lower+1 always. So scatter targets
//     advance by 0/1 per atom -> a sliding 2-register accumulator (accL,accU)
//     emits every output bin exactly once, in increasing order, as a plain
//     ds_write_b32 into the thread's own row (exclusive ownership, in-place
//     over the already-consumed input). No atomics, no RMW, no pre-zeroing.

namespace {

constexpr int NA    = 51;
constexpr int BLOCK = 256;           // threads per block == rows per block
constexpr int ELEMS = BLOCK * NA;    // 13056 floats = 52,224 B LDS

__global__ __launch_bounds__(BLOCK)
void c51_project(const float* __restrict__ next_dist,
                 const float* __restrict__ rewards,
                 const float* __restrict__ bootstrap,
                 float* __restrict__ out,
                 int B)
{
    __shared__ __align__(16) float lds[ELEMS];

    const int tid        = threadIdx.x;
    const int base_row   = blockIdx.x * BLOCK;
    const int rows_here  = min(BLOCK, B - base_row);
    const int elems_here = rows_here * NA;
    const long long base_elem = (long long)base_row * NA;

    // Hoist the per-row scalars so the loads fly during staging + barrier.
    float r = 0.0f, g = 0.0f;
    if (tid < rows_here) {
        r = rewards[base_row + tid];
        g = bootstrap[base_row + tid] * 0.99f;   // bootstrap * DISCOUNT
    }

    // Phase 1: coalesced global -> LDS staging (flat, same layout as global)
    if (elems_here == ELEMS) {
        const float4* __restrict__ in4 = (const float4*)(next_dist + base_elem);
        float4* l4 = (float4*)lds;
        #pragma unroll
        for (int v = tid; v < ELEMS / 4; v += BLOCK) l4[v] = in4[v];
    } else {
        for (int e = tid; e < elems_here; e += BLOCK)
            lds[e] = next_dist[base_elem + e];
    }
    __syncthreads();

    // Phase 2: each thread projects its own row, entirely without atomics.
    if (tid < rows_here) {
        const int rb = tid * NA;

        float d[NA];
        #pragma unroll
        for (int j = 0; j < NA; ++j) d[j] = lds[rb + j];   // static unroll -> regs

        int   cur  = 0;
        float accL = 0.0f, accU = 0.0f;

        #pragma unroll
        for (int j = 0; j < NA; ++j) {
            const float z = fmaf((float)j, 0.4f, -10.0f);  // support atom z_j
            float t = fmaf(g, z, r);                       // r + 0.99*beta*z_j
            t = fminf(fmaxf(t, -10.0f), 10.0f);
            const float b = (t + 10.0f) * 2.5f;            // in [0, 50]

            const float lf = floorf(b);
            int lower = (int)lf;
            if (b == lf && lower > 0) lower -= 1;          // integer-bin adjust
            // post-adjust invariant: upper == lower + 1, lower in [0,49]

            const float wl = d[j] * ((float)(lower + 1) - b);
            const float wu = d[j] * (b - (float)lower);

            // bins strictly below 'lower' are finalized -> emit (covers the
            // leading zero bins too, since cur starts at 0 with accL=0)
            while (cur < lower) {
                lds[rb + cur] = accL;
                accL = accU;
                accU = 0.0f;
                ++cur;
            }
            accL += wl;
            accU += wu;
        }
        lds[rb + cur]     = accL;
        lds[rb + cur + 1] = accU;                          // cur+1 <= 50
        for (int k = cur + 2; k < NA; ++k) lds[rb + k] = 0.0f;  // trailing zeros
    }
    __syncthreads();

    // Phase 3: coalesced LDS -> global
    if (elems_here == ELEMS) {
        float4* __restrict__ o4 = (float4*)(out + base_elem);
        const float4* __restrict__ a4 = (const float4*)lds;
        #pragma unroll
        for (int v = tid; v < ELEMS / 4; v += BLOCK) o4[v] = a4[v];
    } else {
        for (int e = tid; e < elems_here; e += BLOCK)
            out[base_elem + e] = lds[e];
    }
}

} // namespace

extern "C" void kernel_launch(void* const* d_in, const int* in_sizes, int n_in,
                              void* d_out, int out_size, void* d_ws, size_t ws_size,
                              hipStream_t stream)
{
    const float* next_dist = (const float*)d_in[0];
    const float* rewards   = (const float*)d_in[1];
    const float* bootstrap = (const float*)d_in[2];
    float* out = (float*)d_out;

    const int B = in_sizes[1];                    // rewards element count
    const int nblocks = (B + BLOCK - 1) / BLOCK;  // 2048 for B=524288

    c51_project<<<dim3(nblocks), dim3(BLOCK), 0, stream>>>(
        next_dist, rewards, bootstrap, out, B);
}

// Round 4
// 53.984 us; speedup vs baseline: 5.4529x; 1.0025x over previous
//
#include <hip/hip_runtime.h>

// C51 distributional projection — zero-atomic, wave-independent pipelines.
//
// R3 evidence: zero-atomic sliding-scan kernel hit 54 us (floor ~35 us) with
// VALUBusy ~33%, HBM ~48% of achievable, occupancy 28% — nothing saturated.
// Limiter: 256-thread blocks couple 4 waves through __syncthreads and only ~3
// blocks fit per CU, so phases (load/compute/store) serialize with too few
// independently-phased pipelines to keep HBM busy. This version makes each
// WAVE a block: 64 threads own 64 rows + a private 13 KB LDS slab; barriers
// degenerate to wave-local waits; ~12 independent pipelines per CU in
// staggered phases keep memory traffic continuous.
//
//   - slab is flat row-major == global layout: staging in and storing out are
//     contiguous coalesced float4 streams.
//   - each lane owns one row: reads its 51 atoms to registers (static unroll),
//     runs the monotone sliding 2-register scan (b_j has step 0.99 < 1, so
//     after the integer-bin adjust upper == lower+1 and targets advance by
//     0/1), emitting each output bin exactly once as a plain ds_write — no
//     atomics, no RMW, no pre-zeroing. Output overwrites the slab in place.

namespace {

constexpr int NA    = 51;
constexpr int BLOCK = 64;            // one wave; threads == rows per block
constexpr int ELEMS = BLOCK * NA;    // 3264 floats = 13,056 B LDS
constexpr int VECS  = ELEMS / 4;     // 816

__global__ __launch_bounds__(BLOCK)
void c51_project(const float* __restrict__ next_dist,
                 const float* __restrict__ rewards,
                 const float* __restrict__ bootstrap,
                 float* __restrict__ out,
                 int B)
{
    __shared__ __align__(16) float lds[ELEMS];

    const int tid        = threadIdx.x;
    const int base_row   = blockIdx.x * BLOCK;
    const int rows_here  = min(BLOCK, B - base_row);
    const int elems_here = rows_here * NA;
    const long long base_elem = (long long)base_row * NA;

    // Per-row scalars: coalesced 64-wide loads, in flight during staging.
    float r = 0.0f, g = 0.0f;
    if (tid < rows_here) {
        r = rewards[base_row + tid];
        g = bootstrap[base_row + tid] * 0.99f;   // bootstrap * DISCOUNT
    }

    // Phase 1: coalesced global -> LDS staging (flat, same layout as global)
    if (elems_here == ELEMS) {
        const float4* __restrict__ in4 = (const float4*)(next_dist + base_elem);
        float4* l4 = (float4*)lds;
        #pragma unroll
        for (int v = tid; v < VECS; v += BLOCK) l4[v] = in4[v];
    } else {
        for (int e = tid; e < elems_here; e += BLOCK)
            lds[e] = next_dist[base_elem + e];
    }
    __syncthreads();   // single-wave workgroup: wave-local wait, no coupling

    // Phase 2: each lane projects its own row, without atomics.
    if (tid < rows_here) {
        const int rb = tid * NA;

        float d[NA];
        #pragma unroll
        for (int j = 0; j < NA; ++j) d[j] = lds[rb + j];   // static -> regs

        int   cur  = 0;
        float accL = 0.0f, accU = 0.0f;

        #pragma unroll
        for (int j = 0; j < NA; ++j) {
            const float z = fmaf((float)j, 0.4f, -10.0f);  // support atom z_j
            float t = fmaf(g, z, r);                       // r + 0.99*beta*z_j
            t = fminf(fmaxf(t, -10.0f), 10.0f);
            const float b = (t + 10.0f) * 2.5f;            // in [0, 50]

            const float lf = floorf(b);
            int lower = (int)lf;
            if (b == lf && lower > 0) lower -= 1;          // integer-bin adjust
            // post-adjust invariant: upper == lower + 1, lower in [0,49]

            const float wl = d[j] * ((float)(lower + 1) - b);
            const float wu = d[j] * (b - (float)lower);

            // bins strictly below 'lower' are finalized -> emit (covers
            // leading zero bins too: cur starts at 0 with accL=0)
            while (cur < lower) {
                lds[rb + cur] = accL;
                accL = accU;
                accU = 0.0f;
                ++cur;
            }
            accL += wl;
            accU += wu;
        }
        lds[rb + cur]     = accL;
        lds[rb + cur + 1] = accU;                          // cur+1 <= 50
        for (int k = cur + 2; k < NA; ++k) lds[rb + k] = 0.0f;
    }
    __syncthreads();

    // Phase 3: coalesced LDS -> global
    if (elems_here == ELEMS) {
        float4* __restrict__ o4 = (float4*)(out + base_elem);
        const float4* __restrict__ a4 = (const float4*)lds;
        #pragma unroll
        for (int v = tid; v < VECS; v += BLOCK) o4[v] = a4[v];
    } else {
        for (int e = tid; e < elems_here; e += BLOCK)
            out[base_elem + e] = lds[e];
    }
}

} // namespace

extern "C" void kernel_launch(void* const* d_in, const int* in_sizes, int n_in,
                              void* d_out, int out_size, void* d_ws, size_t ws_size,
                              hipStream_t stream)
{
    const float* next_dist = (const float*)d_in[0];
    const float* rewards   = (const float*)d_in[1];
    const float* bootstrap = (const float*)d_in[2];
    float* out = (float*)d_out;

    const int B = in_sizes[1];                    // rewards element count
    const int nblocks = (B + BLOCK - 1) / BLOCK;  // 8192 for B=524288

    c51_project<<<dim3(nblocks), dim3(BLOCK), 0, stream>>>(
        next_dist, rewards, bootstrap, out, B);
}